// Round 12
// baseline (244.136 us; speedup 1.0000x reference)
//
#include <hip/hip_runtime.h>
#include <hip/hip_bf16.h>

#define N_NODES 100000
#define N_EDGES 1600000
#define NBUCK 391          // ceil(N_NODES / 256)
#define NBLK 256           // bucket-phase blocks
#define CHUNK (N_EDGES / NBLK)   // 6250, exact
#define MATP (NBUCK * NBLK)      // 100096, per-part count-matrix size

typedef float f32x4 __attribute__((ext_vector_type(4)));
typedef unsigned short u16x8 __attribute__((ext_vector_type(8)));
typedef _Float16 f16x8 __attribute__((ext_vector_type(8)));

// ---------------- fused setup: bucket histograms + weight transpose (f16) --
__device__ __forceinline__ void wt_elem(const float* __restrict__ W,
                                        _Float16* __restrict__ WTf,
                                        int K, int i) {
    int col = i / K, k = i - col * K;
    WTf[i] = (_Float16)W[(size_t)k * 128 + col];
}

__global__ __launch_bounds__(256) void fused_setup(
    const int* __restrict__ esrc, const int* __restrict__ edst,
    int* __restrict__ cnt_mat,
    const float* __restrict__ W1, _Float16* __restrict__ WT1f,
    const float* __restrict__ W2, _Float16* __restrict__ WT2f)
{
    __shared__ int hd[NBUCK], hs[NBUCK];
    const int b = blockIdx.x, t = threadIdx.x;
    if (b < NBLK) {
        for (int i = t; i < NBUCK; i += 256) { hd[i] = 0; hs[i] = 0; }
        __syncthreads();
        const int e1 = (b + 1) * CHUNK;
        for (int e = b * CHUNK + t; e < e1; e += 256) {
            atomicAdd(&hd[edst[e] >> 8], 1);
            atomicAdd(&hs[esrc[e] >> 8], 1);
        }
        __syncthreads();
        for (int i = t; i < NBUCK; i += 256) {
            cnt_mat[i * NBLK + b] = hd[i];
            cnt_mat[MATP + i * NBLK + b] = hs[i];
        }
    } else {
        int i = (b - NBLK) * 256 + t;         // 0..49151
        if (i < 128 * 256) {
            wt_elem(W1, WT1f, 256, i);
        } else {
            int j = i - 128 * 256;            // < 16384
            wt_elem(W2, WT2f, 128, j);
        }
    }
}

// ---------------- flat exclusive scan (partials applied inline) ----------
__global__ __launch_bounds__(1024) void scan_blocks(const int* __restrict__ counts,
                                                    int* __restrict__ out,
                                                    int* __restrict__ partials, int n) {
    __shared__ int tmp[1024];
    int i = blockIdx.x * 1024 + threadIdx.x;
    int v = (i < n) ? counts[i] : 0;
    tmp[threadIdx.x] = v;
    __syncthreads();
    for (int off = 1; off < 1024; off <<= 1) {
        int t = (threadIdx.x >= (unsigned)off) ? tmp[threadIdx.x - off] : 0;
        __syncthreads();
        tmp[threadIdx.x] += t;
        __syncthreads();
    }
    if (i < n) out[i] = tmp[threadIdx.x] - v;
    if (threadIdx.x == 1023) partials[blockIdx.x] = tmp[1023];
}

// parallel one-block exclusive scan over nb (<256) partials
__global__ __launch_bounds__(256) void scan_partials(int* __restrict__ partials, int nb) {
    __shared__ int tmp[256];
    int t = threadIdx.x;
    int v = (t < nb) ? partials[t] : 0;
    tmp[t] = v;
    __syncthreads();
    for (int off = 1; off < 256; off <<= 1) {
        int u = (t >= off) ? tmp[t - off] : 0;
        __syncthreads();
        tmp[t] += u;
        __syncthreads();
    }
    if (t < nb) partials[t] = tmp[t] - v;  // exclusive
}

__device__ __forceinline__ int sm_at(const int* __restrict__ scan_mat,
                                     const int* __restrict__ partials, int i) {
    return scan_mat[i] + partials[i >> 10];
}

// ---------------- phase 2: scatter edges into bucket-sorted streams ------
__global__ __launch_bounds__(256) void bucket_scatter(const int* __restrict__ esrc,
                                                      const int* __restrict__ edst,
                                                      const int* __restrict__ scan_mat,
                                                      const int* __restrict__ partials,
                                                      unsigned int* __restrict__ tmp) {
    __shared__ int cd[NBUCK], cs[NBUCK];
    const int b = blockIdx.x, t = threadIdx.x;
    for (int i = t; i < NBUCK; i += 256) {
        cd[i] = sm_at(scan_mat, partials, i * NBLK + b);
        cs[i] = sm_at(scan_mat, partials, MATP + i * NBLK + b);
    }
    __syncthreads();
    const int e1 = (b + 1) * CHUNK;
    for (int e = b * CHUNK + t; e < e1; e += 256) {
        int s = esrc[e], d = edst[e];
        int pd = atomicAdd(&cd[d >> 8], 1);
        tmp[pd] = ((unsigned int)(d & 255) << 17) | (unsigned int)s;
        int ps = atomicAdd(&cs[s >> 8], 1);
        tmp[ps] = (unsigned int)s;
    }
}

// ---------------- phase 3: fused per-bucket finalize (dst + src) ---------
__global__ __launch_bounds__(256) void finalize_fused(
    const unsigned int* __restrict__ tmp,
    const int* __restrict__ scan_mat,
    const int* __restrict__ partials,
    int* __restrict__ rowptr,
    int* __restrict__ csr_src,
    float* __restrict__ ndst,
    float* __restrict__ nsrc)
{
    __shared__ int hist[256];
    __shared__ int scn[256];
    __shared__ int cur[256];
    const int bb = blockIdx.x, t = threadIdx.x;
    if (bb < NBUCK) {
        const int b = bb;
        const int beg = sm_at(scan_mat, partials, b * 256);
        const int end = sm_at(scan_mat, partials, (b + 1) * 256);
        hist[t] = 0;
        __syncthreads();
        for (int j = beg + t; j < end; j += 256)
            atomicAdd(&hist[tmp[j] >> 17], 1);
        __syncthreads();
        int v = hist[t];
        scn[t] = v;
        __syncthreads();
        for (int off = 1; off < 256; off <<= 1) {
            int u = (t >= off) ? scn[t - off] : 0;
            __syncthreads();
            scn[t] += u;
            __syncthreads();
        }
        int excl = scn[t] - v;
        int node = b * 256 + t;
        if (node <= N_NODES) rowptr[node] = beg + excl;
        if (node < N_NODES) ndst[node] = rsqrtf(fmaxf((float)v, 1.0f));
        cur[t] = beg + excl;
        __syncthreads();
        for (int j = beg + t; j < end; j += 256) {
            unsigned int x = tmp[j];
            int pos = atomicAdd(&cur[x >> 17], 1);
            csr_src[pos] = (int)(x & 0x1FFFFu);
        }
    } else {
        const int b = bb - NBUCK;
        const int beg = sm_at(scan_mat, partials, MATP + b * 256);
        const int end = (b < NBUCK - 1) ? sm_at(scan_mat, partials, MATP + (b + 1) * 256)
                                        : 2 * N_EDGES;
        hist[t] = 0;
        __syncthreads();
        for (int j = beg + t; j < end; j += 256)
            atomicAdd(&hist[tmp[j] & 255u], 1);
        __syncthreads();
        int node = b * 256 + t;
        if (node < N_NODES) nsrc[node] = rsqrtf(fmaxf((float)hist[t], 1.0f));
    }
}

// ---------------- layer-1 MFMA GEMM (f16 2-term A split, f16 W) ----------
// BM=64, BN=128, BK=32; 4 waves (2x2). LDS slot-major, strides ≡ 4 mod 32 banks.
template<int K>
__global__ __launch_bounds__(256) void gemm_mfma(
    const float* __restrict__ A,            // [M, K] f32
    const _Float16* __restrict__ WTf,       // [128][K] f16 (transposed W)
    const float* __restrict__ rowscale,     // [M]
    _Float16* __restrict__ C16,             // [M, 128] f16 out
    int M)
{
    constexpr int ASTR = 520;   // 64*8 + 8
    constexpr int BSTR = 1032;  // 128*8 + 8
    __shared__ _Float16 Ah[4 * ASTR];
    __shared__ _Float16 Al[4 * ASTR];
    __shared__ _Float16 Bf[4 * BSTR];

    const int tid = threadIdx.x;
    const int bm = blockIdx.x * 64;
    const int lane = tid & 63;
    const int wid = tid >> 6;
    const int wm = wid >> 1;
    const int wn = wid & 1;
    const int lr = lane & 15;
    const int lg = lane >> 4;

    const int st_ar = tid >> 2;
    const int st_s8 = tid & 3;
    const int a_row_g = bm + st_ar;

    f32x4 acc[2][4];
    #pragma unroll
    for (int i = 0; i < 2; ++i)
        #pragma unroll
        for (int j = 0; j < 4; ++j)
            acc[i][j] = (f32x4){0.f, 0.f, 0.f, 0.f};

    float avreg[8];
    f16x8 bv[2];

    auto load_tile = [&](int k0) {
        if (a_row_g < M) {
            const float* ap = &A[(size_t)a_row_g * K + k0 + st_s8 * 8];
            float4 v0 = *reinterpret_cast<const float4*>(ap);
            float4 v1 = *reinterpret_cast<const float4*>(ap + 4);
            avreg[0] = v0.x; avreg[1] = v0.y; avreg[2] = v0.z; avreg[3] = v0.w;
            avreg[4] = v1.x; avreg[5] = v1.y; avreg[6] = v1.z; avreg[7] = v1.w;
        } else {
            #pragma unroll
            for (int j = 0; j < 8; ++j) avreg[j] = 0.f;
        }
        #pragma unroll
        for (int i = 0; i < 2; ++i) {
            int lin = tid + i * 256;
            int col = lin >> 2;
            int s8  = lin & 3;
            bv[i] = *reinterpret_cast<const f16x8*>(&WTf[(size_t)col * K + k0 + s8 * 8]);
        }
    };

    load_tile(0);

    for (int k0 = 0; k0 < K; k0 += 32) {
        {
            int off = st_s8 * ASTR + st_ar * 8;
            f16x8 vh, vl;
            #pragma unroll
            for (int j = 0; j < 8; ++j) {
                _Float16 h = (_Float16)avreg[j];
                vh[j] = h;
                vl[j] = (_Float16)(avreg[j] - (float)h);
            }
            *reinterpret_cast<f16x8*>(&Ah[off]) = vh;
            *reinterpret_cast<f16x8*>(&Al[off]) = vl;
            #pragma unroll
            for (int i = 0; i < 2; ++i) {
                int lin = tid + i * 256;
                int col = lin >> 2;
                int s8  = lin & 3;
                *reinterpret_cast<f16x8*>(&Bf[s8 * BSTR + col * 8]) = bv[i];
            }
        }
        __syncthreads();

        if (k0 + 32 < K) load_tile(k0 + 32);

        {
            f16x8 afh[2], afl[2], bf[4];
            #pragma unroll
            for (int mt = 0; mt < 2; ++mt) {
                int row = wm * 32 + mt * 16 + lr;
                int off = lg * ASTR + row * 8;
                afh[mt] = *reinterpret_cast<const f16x8*>(&Ah[off]);
                afl[mt] = *reinterpret_cast<const f16x8*>(&Al[off]);
            }
            #pragma unroll
            for (int nt = 0; nt < 4; ++nt) {
                int col = wn * 64 + nt * 16 + lr;
                bf[nt] = *reinterpret_cast<const f16x8*>(&Bf[lg * BSTR + col * 8]);
            }
            #pragma unroll
            for (int mt = 0; mt < 2; ++mt) {
                #pragma unroll
                for (int nt = 0; nt < 4; ++nt) {
                    acc[mt][nt] = __builtin_amdgcn_mfma_f32_16x16x32_f16(
                        afh[mt], bf[nt], acc[mt][nt], 0, 0, 0);
                    acc[mt][nt] = __builtin_amdgcn_mfma_f32_16x16x32_f16(
                        afl[mt], bf[nt], acc[mt][nt], 0, 0, 0);
                }
            }
        }
        __syncthreads();
    }

    #pragma unroll
    for (int mt = 0; mt < 2; ++mt) {
        #pragma unroll
        for (int r = 0; r < 4; ++r) {
            int row = bm + wm * 32 + mt * 16 + lg * 4 + r;
            if (row < M) {
                float s = rowscale[row];
                #pragma unroll
                for (int nt = 0; nt < 4; ++nt) {
                    int col = wn * 64 + nt * 16 + lr;
                    C16[(size_t)row * 128 + col] = (_Float16)(acc[mt][nt][r] * s);
                }
            }
        }
    }
}

// ---------------- FUSED: aggregate(h16) -> relu -> x W2 -> nsrc -> h2 ----
// Block = 64 nodes, 256 threads (16 groups x 16 lanes; group owns 4 nodes).
// Phase A: stage full W2^T (128x128 f16) into LDS.
// Phase B: in-block aggregate rows -> relu(agg*ndst+b1) -> LDS A (slot-major).
// Phase C: K=128 MFMA loop, A/B LDS-resident, no per-step barriers.
__global__ __launch_bounds__(256) void fused_ag2(
    const _Float16* __restrict__ h16,       // [N][128] layer-1 gemm out
    const int* __restrict__ rowptr,
    const int* __restrict__ csr_src,
    const float* __restrict__ ndst,
    const float* __restrict__ bias1,        // [128]
    const _Float16* __restrict__ WT2f,      // [128][128] f16 W2^T
    const float* __restrict__ nsrc,
    _Float16* __restrict__ h2,              // [N][128] f16 out
    int N)
{
    constexpr int ASTR = 520;   // 64*8 + 8  (16 slots)
    constexpr int BSTR = 1032;  // 128*8 + 8 (16 slots)
    __shared__ _Float16 Af[16 * ASTR];
    __shared__ _Float16 Bf[16 * BSTR];

    const int tid = threadIdx.x;
    const int bm = blockIdx.x * 64;

    // ---- phase A: stage W2^T (16384 f16 = 2048 f16x8; 8 per thread) ----
    #pragma unroll
    for (int it = 0; it < 8; ++it) {
        int e = it * 256 + tid;          // 0..2047
        int col = e >> 4;                // 0..127
        int sk  = e & 15;                // k-slot
        f16x8 v = *reinterpret_cast<const f16x8*>(&WT2f[(size_t)col * 128 + sk * 8]);
        *reinterpret_cast<f16x8*>(&Bf[sk * BSTR + col * 8]) = v;
    }

    // ---- phase B: aggregate 4 nodes per 16-lane group ----
    {
        const int grp = tid >> 4;        // 0..15
        const int l   = tid & 15;        // lane in group; owns cols l*8..l*8+7
        const int c8  = l * 8;
        const float4 bb0 = *reinterpret_cast<const float4*>(&bias1[c8]);
        const float4 bb1 = *reinterpret_cast<const float4*>(&bias1[c8 + 4]);
        #pragma unroll
        for (int i = 0; i < 4; ++i) {
            int rloc = grp * 4 + i;
            int node = bm + rloc;
            float acc[8] = {0.f, 0.f, 0.f, 0.f, 0.f, 0.f, 0.f, 0.f};
            if (node < N) {
                int beg = rowptr[node];
                int end = rowptr[node + 1];
                int j = beg;
                for (; j + 3 < end; j += 4) {
                    int s0 = csr_src[j];
                    int s1 = csr_src[j + 1];
                    int s2 = csr_src[j + 2];
                    int s3 = csr_src[j + 3];
                    f16x8 v0 = *reinterpret_cast<const f16x8*>(&h16[(size_t)s0 * 128 + c8]);
                    f16x8 v1 = *reinterpret_cast<const f16x8*>(&h16[(size_t)s1 * 128 + c8]);
                    f16x8 v2 = *reinterpret_cast<const f16x8*>(&h16[(size_t)s2 * 128 + c8]);
                    f16x8 v3 = *reinterpret_cast<const f16x8*>(&h16[(size_t)s3 * 128 + c8]);
                    #pragma unroll
                    for (int k = 0; k < 8; ++k)
                        acc[k] += ((float)v0[k] + (float)v1[k]) + ((float)v2[k] + (float)v3[k]);
                }
                for (; j < end; ++j) {
                    int s0 = csr_src[j];
                    f16x8 v0 = *reinterpret_cast<const f16x8*>(&h16[(size_t)s0 * 128 + c8]);
                    #pragma unroll
                    for (int k = 0; k < 8; ++k) acc[k] += (float)v0[k];
                }
                float sc = ndst[node];
                acc[0] = fmaxf(acc[0] * sc + bb0.x, 0.f);
                acc[1] = fmaxf(acc[1] * sc + bb0.y, 0.f);
                acc[2] = fmaxf(acc[2] * sc + bb0.z, 0.f);
                acc[3] = fmaxf(acc[3] * sc + bb0.w, 0.f);
                acc[4] = fmaxf(acc[4] * sc + bb1.x, 0.f);
                acc[5] = fmaxf(acc[5] * sc + bb1.y, 0.f);
                acc[6] = fmaxf(acc[6] * sc + bb1.z, 0.f);
                acc[7] = fmaxf(acc[7] * sc + bb1.w, 0.f);
            }
            f16x8 av;
            #pragma unroll
            for (int k = 0; k < 8; ++k) av[k] = (_Float16)acc[k];
            // slot = l (cols l*8..l*8+7), row = rloc
            *reinterpret_cast<f16x8*>(&Af[l * ASTR + rloc * 8]) = av;
        }
    }
    __syncthreads();

    // ---- phase C: MFMA, K=128 in 4 steps, no staging barriers ----
    const int lane = tid & 63;
    const int wid = tid >> 6;
    const int wm = wid >> 1;
    const int wn = wid & 1;
    const int lr = lane & 15;
    const int lg = lane >> 4;

    f32x4 acc[2][4];
    #pragma unroll
    for (int i = 0; i < 2; ++i)
        #pragma unroll
        for (int j = 0; j < 4; ++j)
            acc[i][j] = (f32x4){0.f, 0.f, 0.f, 0.f};

    #pragma unroll
    for (int ks = 0; ks < 4; ++ks) {
        const int slot = ks * 4 + lg;
        f16x8 af[2], bf[4];
        #pragma unroll
        for (int mt = 0; mt < 2; ++mt) {
            int row = wm * 32 + mt * 16 + lr;
            af[mt] = *reinterpret_cast<const f16x8*>(&Af[slot * ASTR + row * 8]);
        }
        #pragma unroll
        for (int nt = 0; nt < 4; ++nt) {
            int col = wn * 64 + nt * 16 + lr;
            bf[nt] = *reinterpret_cast<const f16x8*>(&Bf[slot * BSTR + col * 8]);
        }
        #pragma unroll
        for (int mt = 0; mt < 2; ++mt)
            #pragma unroll
            for (int nt = 0; nt < 4; ++nt)
                acc[mt][nt] = __builtin_amdgcn_mfma_f32_16x16x32_f16(
                    af[mt], bf[nt], acc[mt][nt], 0, 0, 0);
    }

    // ---- epilogue: nsrc rowscale, store f16 ----
    #pragma unroll
    for (int mt = 0; mt < 2; ++mt) {
        #pragma unroll
        for (int r = 0; r < 4; ++r) {
            int row = bm + wm * 32 + mt * 16 + lg * 4 + r;
            if (row < N) {
                float s = nsrc[row];
                #pragma unroll
                for (int nt = 0; nt < 4; ++nt) {
                    int col = wn * 64 + nt * 16 + lr;
                    h2[(size_t)row * 128 + col] = (_Float16)(acc[mt][nt][r] * s);
                }
            }
        }
    }
}

// ---------------- CSR aggregation, both column halves in ONE dispatch ----
__global__ __launch_bounds__(256) void aggregate_full(
    const _Float16* __restrict__ h16,
    const int* __restrict__ rowptr,
    const int* __restrict__ csr_src,
    const float* __restrict__ ndst,
    const float* __restrict__ bias,
    float* __restrict__ out, int N, int half_blocks)
{
    int b = blockIdx.x;
    int c_base = 0;
    if (b >= half_blocks) { c_base = 64; b -= half_blocks; }
    int g = b * blockDim.x + threadIdx.x;
    int node = g >> 3;
    if (node >= N) return;
    int c8 = ((g & 7) * 8) + c_base;
    int beg = rowptr[node];
    int end = rowptr[node + 1];
    float acc[8] = {0.f, 0.f, 0.f, 0.f, 0.f, 0.f, 0.f, 0.f};
    int j = beg;
    for (; j + 3 < end; j += 4) {
        int s0 = csr_src[j];
        int s1 = csr_src[j + 1];
        int s2 = csr_src[j + 2];
        int s3 = csr_src[j + 3];
        f16x8 v0 = *reinterpret_cast<const f16x8*>(&h16[(size_t)s0 * 128 + c8]);
        f16x8 v1 = *reinterpret_cast<const f16x8*>(&h16[(size_t)s1 * 128 + c8]);
        f16x8 v2 = *reinterpret_cast<const f16x8*>(&h16[(size_t)s2 * 128 + c8]);
        f16x8 v3 = *reinterpret_cast<const f16x8*>(&h16[(size_t)s3 * 128 + c8]);
        #pragma unroll
        for (int k = 0; k < 8; ++k)
            acc[k] += ((float)v0[k] + (float)v1[k]) + ((float)v2[k] + (float)v3[k]);
    }
    for (; j < end; ++j) {
        int s0 = csr_src[j];
        f16x8 v0 = *reinterpret_cast<const f16x8*>(&h16[(size_t)s0 * 128 + c8]);
        #pragma unroll
        for (int k = 0; k < 8; ++k) acc[k] += (float)v0[k];
    }
    float sc = ndst[node];
    const float4 b0 = *reinterpret_cast<const float4*>(&bias[c8]);
    const float4 b1 = *reinterpret_cast<const float4*>(&bias[c8 + 4]);
    float4 r0, r1;
    r0.x = fmaxf(acc[0] * sc + b0.x, 0.f);
    r0.y = fmaxf(acc[1] * sc + b0.y, 0.f);
    r0.z = fmaxf(acc[2] * sc + b0.z, 0.f);
    r0.w = fmaxf(acc[3] * sc + b0.w, 0.f);
    r1.x = fmaxf(acc[4] * sc + b1.x, 0.f);
    r1.y = fmaxf(acc[5] * sc + b1.y, 0.f);
    r1.z = fmaxf(acc[6] * sc + b1.z, 0.f);
    r1.w = fmaxf(acc[7] * sc + b1.w, 0.f);
    float* op = &out[(size_t)node * 128 + c8];
    *reinterpret_cast<float4*>(op) = r0;
    *reinterpret_cast<float4*>(op + 4) = r1;
}

extern "C" void kernel_launch(void* const* d_in, const int* in_sizes, int n_in,
                              void* d_out, int out_size, void* d_ws, size_t ws_size,
                              hipStream_t stream) {
    const float* feat = (const float*)d_in[0];   // [1, N, 256]
    const float* W1   = (const float*)d_in[1];   // [256, 128]
    const float* b1   = (const float*)d_in[2];   // [128]
    const float* W2   = (const float*)d_in[3];   // [128, 128]
    const float* b2   = (const float*)d_in[4];   // [128]
    const int* esrc   = (const int*)d_in[5];     // [E]
    const int* edst   = (const int*)d_in[6];     // [E]
    float* out = (float*)d_out;                  // [N, 128]

    const int Nn = N_NODES, E = N_EDGES;
    const int SCAN_N = 2 * MATP;                 // 200192
    const int SCAN_NB = (SCAN_N + 1023) / 1024;  // 196

    // workspace: h slot (N*128 f32-sized) holds h16 + h2 (both f16)
    float* hseg   = (float*)d_ws;
    _Float16* h16 = (_Float16*)hseg;
    _Float16* h2  = h16 + (size_t)Nn * 128;
    _Float16* WT1f = (_Float16*)(hseg + (size_t)Nn * 128);
    _Float16* WT2f = WT1f + 128 * 256;
    int* csr_src  = (int*)(WT2f + 128 * 128);
    int* rowptr   = csr_src + E;
    unsigned int* tmp = (unsigned int*)(rowptr + 100004);
    int* cnt_mat  = (int*)(tmp + 2 * (size_t)E);
    int* scan_mat = cnt_mat + SCAN_N;
    int* partials = scan_mat + SCAN_N;
    float* nsrc   = (float*)(partials + ((SCAN_NB + 3) & ~3));
    float* ndst   = nsrc + Nn;

    // --- setup: bucket histograms + weight transpose (f16) fused ---
    fused_setup<<<NBLK + 192, 256, 0, stream>>>(esrc, edst, cnt_mat, W1, WT1f, W2, WT2f);

    // --- scan ---
    scan_blocks<<<SCAN_NB, 1024, 0, stream>>>(cnt_mat, scan_mat, partials, SCAN_N);
    scan_partials<<<1, 256, 0, stream>>>(partials, SCAN_NB);

    // --- scatter + fused finalize ---
    bucket_scatter<<<NBLK, 256, 0, stream>>>(esrc, edst, scan_mat, partials, tmp);
    finalize_fused<<<2 * NBUCK, 256, 0, stream>>>(tmp, scan_mat, partials,
                                                  rowptr, csr_src, ndst, nsrc);

    const int gemm_grid = (Nn + 63) / 64;        // 1563
    const int aggh_grid = (Nn * 8 + 255) / 256;  // 3125

    // --- layer 1 gemm: (nsrc-scaled in epilogue) feat x W1 -> h16 (f16) ---
    gemm_mfma<256><<<gemm_grid, 256, 0, stream>>>(feat, WT1f, nsrc, h16, Nn);

    // --- fused: agg1(h16) -> relu -> x W2 -> nsrc -> h2 (f16) ---
    fused_ag2<<<gemm_grid, 256, 0, stream>>>(h16, rowptr, csr_src, ndst, b1,
                                             WT2f, nsrc, h2, Nn);

    // --- layer 2 aggregate -> d_out (f32) ---
    aggregate_full<<<2 * aggh_grid, 256, 0, stream>>>(
        h2, rowptr, csr_src, ndst, b2, out, Nn, aggh_grid);
}

// Round 13
// 225.406 us; speedup vs baseline: 1.0831x; 1.0831x over previous
//
#include <hip/hip_runtime.h>
#include <hip/hip_bf16.h>

#define N_NODES 100000
#define N_EDGES 1600000
#define NBUCK 391          // ceil(N_NODES / 256)
#define NBLK 256           // bucket-phase blocks
#define CHUNK (N_EDGES / NBLK)   // 6250, exact
#define MATP (NBUCK * NBLK)      // 100096, per-part count-matrix size

typedef float f32x4 __attribute__((ext_vector_type(4)));
typedef unsigned short u16x8 __attribute__((ext_vector_type(8)));
typedef _Float16 f16x8 __attribute__((ext_vector_type(8)));

// ---------------- fused setup: bucket histograms + weight transpose (f16) --
__device__ __forceinline__ void wt_elem(const float* __restrict__ W,
                                        _Float16* __restrict__ WTf,
                                        int K, int i) {
    int col = i / K, k = i - col * K;
    WTf[i] = (_Float16)W[(size_t)k * 128 + col];
}

__global__ __launch_bounds__(256) void fused_setup(
    const int* __restrict__ esrc, const int* __restrict__ edst,
    int* __restrict__ cnt_mat,
    const float* __restrict__ W1, _Float16* __restrict__ WT1f,
    const float* __restrict__ W2, _Float16* __restrict__ WT2f)
{
    __shared__ int hd[NBUCK], hs[NBUCK];
    const int b = blockIdx.x, t = threadIdx.x;
    if (b < NBLK) {
        for (int i = t; i < NBUCK; i += 256) { hd[i] = 0; hs[i] = 0; }
        __syncthreads();
        const int e1 = (b + 1) * CHUNK;
        for (int e = b * CHUNK + t; e < e1; e += 256) {
            atomicAdd(&hd[edst[e] >> 8], 1);
            atomicAdd(&hs[esrc[e] >> 8], 1);
        }
        __syncthreads();
        for (int i = t; i < NBUCK; i += 256) {
            cnt_mat[i * NBLK + b] = hd[i];
            cnt_mat[MATP + i * NBLK + b] = hs[i];
        }
    } else {
        int i = (b - NBLK) * 256 + t;         // 0..49151
        if (i < 128 * 256) {
            wt_elem(W1, WT1f, 256, i);
        } else {
            int j = i - 128 * 256;            // < 16384
            wt_elem(W2, WT2f, 128, j);
        }
    }
}

// ---------------- flat exclusive scan (partials applied inline) ----------
__global__ __launch_bounds__(1024) void scan_blocks(const int* __restrict__ counts,
                                                    int* __restrict__ out,
                                                    int* __restrict__ partials, int n) {
    __shared__ int tmp[1024];
    int i = blockIdx.x * 1024 + threadIdx.x;
    int v = (i < n) ? counts[i] : 0;
    tmp[threadIdx.x] = v;
    __syncthreads();
    for (int off = 1; off < 1024; off <<= 1) {
        int t = (threadIdx.x >= (unsigned)off) ? tmp[threadIdx.x - off] : 0;
        __syncthreads();
        tmp[threadIdx.x] += t;
        __syncthreads();
    }
    if (i < n) out[i] = tmp[threadIdx.x] - v;
    if (threadIdx.x == 1023) partials[blockIdx.x] = tmp[1023];
}

// parallel one-block exclusive scan over nb (<256) partials
__global__ __launch_bounds__(256) void scan_partials(int* __restrict__ partials, int nb) {
    __shared__ int tmp[256];
    int t = threadIdx.x;
    int v = (t < nb) ? partials[t] : 0;
    tmp[t] = v;
    __syncthreads();
    for (int off = 1; off < 256; off <<= 1) {
        int u = (t >= off) ? tmp[t - off] : 0;
        __syncthreads();
        tmp[t] += u;
        __syncthreads();
    }
    if (t < nb) partials[t] = tmp[t] - v;  // exclusive
}

__device__ __forceinline__ int sm_at(const int* __restrict__ scan_mat,
                                     const int* __restrict__ partials, int i) {
    return scan_mat[i] + partials[i >> 10];
}

// ---------------- phase 2: scatter edges into bucket-sorted streams ------
__global__ __launch_bounds__(256) void bucket_scatter(const int* __restrict__ esrc,
                                                      const int* __restrict__ edst,
                                                      const int* __restrict__ scan_mat,
                                                      const int* __restrict__ partials,
                                                      unsigned int* __restrict__ tmp) {
    __shared__ int cd[NBUCK], cs[NBUCK];
    const int b = blockIdx.x, t = threadIdx.x;
    for (int i = t; i < NBUCK; i += 256) {
        cd[i] = sm_at(scan_mat, partials, i * NBLK + b);
        cs[i] = sm_at(scan_mat, partials, MATP + i * NBLK + b);
    }
    __syncthreads();
    const int e1 = (b + 1) * CHUNK;
    for (int e = b * CHUNK + t; e < e1; e += 256) {
        int s = esrc[e], d = edst[e];
        int pd = atomicAdd(&cd[d >> 8], 1);
        tmp[pd] = ((unsigned int)(d & 255) << 17) | (unsigned int)s;
        int ps = atomicAdd(&cs[s >> 8], 1);
        tmp[ps] = (unsigned int)s;
    }
}

// ---------------- phase 3: fused per-bucket finalize (dst + src) ---------
__global__ __launch_bounds__(256) void finalize_fused(
    const unsigned int* __restrict__ tmp,
    const int* __restrict__ scan_mat,
    const int* __restrict__ partials,
    int* __restrict__ rowptr,
    int* __restrict__ csr_src,
    float* __restrict__ ndst,
    float* __restrict__ nsrc)
{
    __shared__ int hist[256];
    __shared__ int scn[256];
    __shared__ int cur[256];
    const int bb = blockIdx.x, t = threadIdx.x;
    if (bb < NBUCK) {
        const int b = bb;
        const int beg = sm_at(scan_mat, partials, b * 256);
        const int end = sm_at(scan_mat, partials, (b + 1) * 256);
        hist[t] = 0;
        __syncthreads();
        for (int j = beg + t; j < end; j += 256)
            atomicAdd(&hist[tmp[j] >> 17], 1);
        __syncthreads();
        int v = hist[t];
        scn[t] = v;
        __syncthreads();
        for (int off = 1; off < 256; off <<= 1) {
            int u = (t >= off) ? scn[t - off] : 0;
            __syncthreads();
            scn[t] += u;
            __syncthreads();
        }
        int excl = scn[t] - v;
        int node = b * 256 + t;
        if (node <= N_NODES) rowptr[node] = beg + excl;
        if (node < N_NODES) ndst[node] = rsqrtf(fmaxf((float)v, 1.0f));
        cur[t] = beg + excl;
        __syncthreads();
        for (int j = beg + t; j < end; j += 256) {
            unsigned int x = tmp[j];
            int pos = atomicAdd(&cur[x >> 17], 1);
            csr_src[pos] = (int)(x & 0x1FFFFu);
        }
    } else {
        const int b = bb - NBUCK;
        const int beg = sm_at(scan_mat, partials, MATP + b * 256);
        const int end = (b < NBUCK - 1) ? sm_at(scan_mat, partials, MATP + (b + 1) * 256)
                                        : 2 * N_EDGES;
        hist[t] = 0;
        __syncthreads();
        for (int j = beg + t; j < end; j += 256)
            atomicAdd(&hist[tmp[j] & 255u], 1);
        __syncthreads();
        int node = b * 256 + t;
        if (node < N_NODES) nsrc[node] = rsqrtf(fmaxf((float)hist[t], 1.0f));
    }
}

// ---------------- MFMA GEMM, f16 operands, f32 accumulate ----------------
// BM=64, BN=128, BK=32; 4 waves (2x2).
// Layer 1 (AT=float, ATERMS=2): A = ah + al (two f16, exact to 2^-22); W = f16.
// Layer 2 (AT=f16, ATERMS=1): A exact f16, single term.
// LDS slot-major [slot][row/col][8], slot strides ≡ 4 (mod 32) dword banks.
template<int K, int ATERMS, typename AT>
__global__ __launch_bounds__(256) void gemm_mfma(
    const AT* __restrict__ A,               // [M, K]
    const _Float16* __restrict__ WTf,       // [128][K] f16 (transposed W)
    const float* __restrict__ rowscale,     // [M]
    _Float16* __restrict__ C16,             // [M, 128] f16 out
    int M)
{
    constexpr int ASTR = 520;   // 64*8 + 8
    constexpr int BSTR = 1032;  // 128*8 + 8
    __shared__ _Float16 Ah[4 * ASTR];
    __shared__ _Float16 Al[ATERMS == 2 ? 4 * ASTR : 8];
    __shared__ _Float16 Bf[4 * BSTR];

    const int tid = threadIdx.x;
    const int bm = blockIdx.x * 64;
    const int lane = tid & 63;
    const int wid = tid >> 6;
    const int wm = wid >> 1;
    const int wn = wid & 1;
    const int lr = lane & 15;
    const int lg = lane >> 4;

    const int st_ar = tid >> 2;
    const int st_s8 = tid & 3;
    const int a_row_g = bm + st_ar;

    f32x4 acc[2][4];
    #pragma unroll
    for (int i = 0; i < 2; ++i)
        #pragma unroll
        for (int j = 0; j < 4; ++j)
            acc[i][j] = (f32x4){0.f, 0.f, 0.f, 0.f};

    float avreg[8];
    f16x8 areg16;
    f16x8 bv[2];

    auto load_tile = [&](int k0) {
        if (a_row_g < M) {
            const AT* ap = &A[(size_t)a_row_g * K + k0 + st_s8 * 8];
            if constexpr (sizeof(AT) == 4) {
                float4 v0 = *reinterpret_cast<const float4*>(ap);
                float4 v1 = *reinterpret_cast<const float4*>(ap + 4);
                avreg[0] = v0.x; avreg[1] = v0.y; avreg[2] = v0.z; avreg[3] = v0.w;
                avreg[4] = v1.x; avreg[5] = v1.y; avreg[6] = v1.z; avreg[7] = v1.w;
            } else {
                areg16 = *reinterpret_cast<const f16x8*>(ap);
            }
        } else {
            if constexpr (sizeof(AT) == 4) {
                #pragma unroll
                for (int j = 0; j < 8; ++j) avreg[j] = 0.f;
            } else {
                #pragma unroll
                for (int j = 0; j < 8; ++j) areg16[j] = (_Float16)0.f;
            }
        }
        #pragma unroll
        for (int i = 0; i < 2; ++i) {
            int lin = tid + i * 256;
            int col = lin >> 2;
            int s8  = lin & 3;
            bv[i] = *reinterpret_cast<const f16x8*>(&WTf[(size_t)col * K + k0 + s8 * 8]);
        }
    };

    load_tile(0);

    for (int k0 = 0; k0 < K; k0 += 32) {
        {
            int off = st_s8 * ASTR + st_ar * 8;
            if constexpr (sizeof(AT) == 4) {
                f16x8 vh, vl;
                #pragma unroll
                for (int j = 0; j < 8; ++j) {
                    _Float16 h = (_Float16)avreg[j];
                    vh[j] = h;
                    vl[j] = (_Float16)(avreg[j] - (float)h);
                }
                *reinterpret_cast<f16x8*>(&Ah[off]) = vh;
                if constexpr (ATERMS == 2)
                    *reinterpret_cast<f16x8*>(&Al[off]) = vl;
            } else {
                *reinterpret_cast<f16x8*>(&Ah[off]) = areg16;
            }
            #pragma unroll
            for (int i = 0; i < 2; ++i) {
                int lin = tid + i * 256;
                int col = lin >> 2;
                int s8  = lin & 3;
                *reinterpret_cast<f16x8*>(&Bf[s8 * BSTR + col * 8]) = bv[i];
            }
        }
        __syncthreads();

        if (k0 + 32 < K) load_tile(k0 + 32);

        {
            f16x8 afh[2], afl[2], bf[4];
            #pragma unroll
            for (int mt = 0; mt < 2; ++mt) {
                int row = wm * 32 + mt * 16 + lr;
                int off = lg * ASTR + row * 8;
                afh[mt] = *reinterpret_cast<const f16x8*>(&Ah[off]);
                if constexpr (ATERMS == 2)
                    afl[mt] = *reinterpret_cast<const f16x8*>(&Al[off]);
            }
            #pragma unroll
            for (int nt = 0; nt < 4; ++nt) {
                int col = wn * 64 + nt * 16 + lr;
                bf[nt] = *reinterpret_cast<const f16x8*>(&Bf[lg * BSTR + col * 8]);
            }
            #pragma unroll
            for (int mt = 0; mt < 2; ++mt) {
                #pragma unroll
                for (int nt = 0; nt < 4; ++nt) {
                    acc[mt][nt] = __builtin_amdgcn_mfma_f32_16x16x32_f16(
                        afh[mt], bf[nt], acc[mt][nt], 0, 0, 0);
                    if constexpr (ATERMS == 2)
                        acc[mt][nt] = __builtin_amdgcn_mfma_f32_16x16x32_f16(
                            afl[mt], bf[nt], acc[mt][nt], 0, 0, 0);
                }
            }
        }
        __syncthreads();
    }

    #pragma unroll
    for (int mt = 0; mt < 2; ++mt) {
        #pragma unroll
        for (int r = 0; r < 4; ++r) {
            int row = bm + wm * 32 + mt * 16 + lg * 4 + r;
            if (row < M) {
                float s = rowscale[row];
                #pragma unroll
                for (int nt = 0; nt < 4; ++nt) {
                    int col = wn * 64 + nt * 16 + lr;
                    C16[(size_t)row * 128 + col] = (_Float16)(acc[mt][nt][r] * s);
                }
            }
        }
    }
}

// ---------------- CSR aggregation, 16 lanes/node single pass -------------
// 16 lanes per node, 8 cols each (full 256B row per node-group); index read once.
template<typename OT>
__global__ __launch_bounds__(256) void aggregate16(
    const _Float16* __restrict__ h16,
    const int* __restrict__ rowptr,
    const int* __restrict__ csr_src,
    const float* __restrict__ ndst,
    const float* __restrict__ bias,
    OT* __restrict__ out, int N)
{
    int g = blockIdx.x * blockDim.x + threadIdx.x;
    int node = g >> 4;
    if (node >= N) return;
    int c8 = (g & 15) * 8;
    int beg = rowptr[node];
    int end = rowptr[node + 1];
    float acc[8] = {0.f, 0.f, 0.f, 0.f, 0.f, 0.f, 0.f, 0.f};
    int j = beg;
    for (; j + 3 < end; j += 4) {
        int s0 = csr_src[j];
        int s1 = csr_src[j + 1];
        int s2 = csr_src[j + 2];
        int s3 = csr_src[j + 3];
        f16x8 v0 = *reinterpret_cast<const f16x8*>(&h16[(size_t)s0 * 128 + c8]);
        f16x8 v1 = *reinterpret_cast<const f16x8*>(&h16[(size_t)s1 * 128 + c8]);
        f16x8 v2 = *reinterpret_cast<const f16x8*>(&h16[(size_t)s2 * 128 + c8]);
        f16x8 v3 = *reinterpret_cast<const f16x8*>(&h16[(size_t)s3 * 128 + c8]);
        #pragma unroll
        for (int k = 0; k < 8; ++k)
            acc[k] += ((float)v0[k] + (float)v1[k]) + ((float)v2[k] + (float)v3[k]);
    }
    for (; j < end; ++j) {
        int s0 = csr_src[j];
        f16x8 v0 = *reinterpret_cast<const f16x8*>(&h16[(size_t)s0 * 128 + c8]);
        #pragma unroll
        for (int k = 0; k < 8; ++k) acc[k] += (float)v0[k];
    }
    float sc = ndst[node];
    const float4 b0 = *reinterpret_cast<const float4*>(&bias[c8]);
    const float4 b1 = *reinterpret_cast<const float4*>(&bias[c8 + 4]);
    float r[8];
    r[0] = fmaxf(acc[0] * sc + b0.x, 0.f);
    r[1] = fmaxf(acc[1] * sc + b0.y, 0.f);
    r[2] = fmaxf(acc[2] * sc + b0.z, 0.f);
    r[3] = fmaxf(acc[3] * sc + b0.w, 0.f);
    r[4] = fmaxf(acc[4] * sc + b1.x, 0.f);
    r[5] = fmaxf(acc[5] * sc + b1.y, 0.f);
    r[6] = fmaxf(acc[6] * sc + b1.z, 0.f);
    r[7] = fmaxf(acc[7] * sc + b1.w, 0.f);
    OT* op = &out[(size_t)node * 128 + c8];
    if constexpr (sizeof(OT) == 4) {
        float4 r0 = {r[0], r[1], r[2], r[3]};
        float4 r1 = {r[4], r[5], r[6], r[7]};
        *reinterpret_cast<float4*>(op) = r0;
        *reinterpret_cast<float4*>(op + 4) = r1;
    } else {
        f16x8 rv;
        #pragma unroll
        for (int k = 0; k < 8; ++k) rv[k] = (_Float16)r[k];
        *reinterpret_cast<f16x8*>(op) = rv;
    }
}

extern "C" void kernel_launch(void* const* d_in, const int* in_sizes, int n_in,
                              void* d_out, int out_size, void* d_ws, size_t ws_size,
                              hipStream_t stream) {
    const float* feat = (const float*)d_in[0];   // [1, N, 256]
    const float* W1   = (const float*)d_in[1];   // [256, 128]
    const float* b1   = (const float*)d_in[2];   // [128]
    const float* W2   = (const float*)d_in[3];   // [128, 128]
    const float* b2   = (const float*)d_in[4];   // [128]
    const int* esrc   = (const int*)d_in[5];     // [E]
    const int* edst   = (const int*)d_in[6];     // [E]
    float* out = (float*)d_out;                  // [N, 128]

    const int Nn = N_NODES, E = N_EDGES;
    const int SCAN_N = 2 * MATP;                 // 200192
    const int SCAN_NB = (SCAN_N + 1023) / 1024;  // 196

    // workspace: h slot (N*128 f32-sized) holds h16 + h1out (both f16)
    float* hseg   = (float*)d_ws;
    _Float16* h16   = (_Float16*)hseg;
    _Float16* h1out = h16 + (size_t)Nn * 128;
    _Float16* WT1f = (_Float16*)(hseg + (size_t)Nn * 128);
    _Float16* WT2f = WT1f + 128 * 256;
    int* csr_src  = (int*)(WT2f + 128 * 128);
    int* rowptr   = csr_src + E;
    unsigned int* tmp = (unsigned int*)(rowptr + 100004);
    int* cnt_mat  = (int*)(tmp + 2 * (size_t)E);
    int* scan_mat = cnt_mat + SCAN_N;
    int* partials = scan_mat + SCAN_N;
    float* nsrc   = (float*)(partials + ((SCAN_NB + 3) & ~3));
    float* ndst   = nsrc + Nn;

    // --- setup: bucket histograms + weight transpose (f16) fused ---
    fused_setup<<<NBLK + 192, 256, 0, stream>>>(esrc, edst, cnt_mat, W1, WT1f, W2, WT2f);

    // --- scan ---
    scan_blocks<<<SCAN_NB, 1024, 0, stream>>>(cnt_mat, scan_mat, partials, SCAN_N);
    scan_partials<<<1, 256, 0, stream>>>(partials, SCAN_NB);

    // --- scatter + fused finalize ---
    bucket_scatter<<<NBLK, 256, 0, stream>>>(esrc, edst, scan_mat, partials, tmp);
    finalize_fused<<<2 * NBUCK, 256, 0, stream>>>(tmp, scan_mat, partials,
                                                  rowptr, csr_src, ndst, nsrc);

    const int gemm_grid = (Nn + 63) / 64;         // 1563
    const int agg_grid  = (Nn * 16 + 255) / 256;  // 6250

    // --- layer 1: gemm (A f32, 2-term) -> h16; aggregate -> h1out (f16) ---
    gemm_mfma<256, 2, float><<<gemm_grid, 256, 0, stream>>>(feat, WT1f, nsrc, h16, Nn);
    aggregate16<_Float16><<<agg_grid, 256, 0, stream>>>(
        h16, rowptr, csr_src, ndst, b1, h1out, Nn);

    // --- layer 2: gemm (A f16, 1-term) -> h16; aggregate -> d_out (f32) ---
    gemm_mfma<128, 1, _Float16><<<gemm_grid, 256, 0, stream>>>(h1out, WT2f, nsrc, h16, Nn);
    aggregate16<float><<<agg_grid, 256, 0, stream>>>(
        h16, rowptr, csr_src, ndst, b2, out, Nn);
}

// Round 14
// 225.317 us; speedup vs baseline: 1.0835x; 1.0004x over previous
//
#include <hip/hip_runtime.h>
#include <hip/hip_bf16.h>

#define N_NODES 100000
#define N_EDGES 1600000
#define NBUCK 391          // ceil(N_NODES / 256)
#define NBLK 256           // bucket-phase blocks
#define CHUNK (N_EDGES / NBLK)   // 6250, exact
#define MATP (NBUCK * NBLK)      // 100096, per-part count-matrix size

typedef float f32x4 __attribute__((ext_vector_type(4)));
typedef _Float16 f16x8 __attribute__((ext_vector_type(8)));

// ---------------- fused setup: bucket histograms + weight transpose (f16) --
__device__ __forceinline__ void wt_elem(const float* __restrict__ W,
                                        _Float16* __restrict__ WTf,
                                        int K, int i) {
    int col = i / K, k = i - col * K;
    WTf[i] = (_Float16)W[(size_t)k * 128 + col];
}

__global__ __launch_bounds__(256) void fused_setup(
    const int* __restrict__ esrc, const int* __restrict__ edst,
    int* __restrict__ cnt_mat,
    const float* __restrict__ W1, _Float16* __restrict__ WT1f,
    const float* __restrict__ W2, _Float16* __restrict__ WT2f)
{
    __shared__ int hd[NBUCK], hs[NBUCK];
    const int b = blockIdx.x, t = threadIdx.x;
    if (b < NBLK) {
        for (int i = t; i < NBUCK; i += 256) { hd[i] = 0; hs[i] = 0; }
        __syncthreads();
        const int e1 = (b + 1) * CHUNK;
        for (int e = b * CHUNK + t; e < e1; e += 256) {
            atomicAdd(&hd[edst[e] >> 8], 1);
            atomicAdd(&hs[esrc[e] >> 8], 1);
        }
        __syncthreads();
        for (int i = t; i < NBUCK; i += 256) {
            cnt_mat[i * NBLK + b] = hd[i];
            cnt_mat[MATP + i * NBLK + b] = hs[i];
        }
    } else {
        int i = (b - NBLK) * 256 + t;         // 0..49151
        if (i < 128 * 256) {
            wt_elem(W1, WT1f, 256, i);
        } else {
            int j = i - 128 * 256;            // < 16384
            wt_elem(W2, WT2f, 128, j);
        }
    }
}

// ---------------- flat exclusive scan (partials applied inline) ----------
__global__ __launch_bounds__(1024) void scan_blocks(const int* __restrict__ counts,
                                                    int* __restrict__ out,
                                                    int* __restrict__ partials, int n) {
    __shared__ int tmp[1024];
    int i = blockIdx.x * 1024 + threadIdx.x;
    int v = (i < n) ? counts[i] : 0;
    tmp[threadIdx.x] = v;
    __syncthreads();
    for (int off = 1; off < 1024; off <<= 1) {
        int t = (threadIdx.x >= (unsigned)off) ? tmp[threadIdx.x - off] : 0;
        __syncthreads();
        tmp[threadIdx.x] += t;
        __syncthreads();
    }
    if (i < n) out[i] = tmp[threadIdx.x] - v;
    if (threadIdx.x == 1023) partials[blockIdx.x] = tmp[1023];
}

// parallel one-block exclusive scan over nb (<256) partials
__global__ __launch_bounds__(256) void scan_partials(int* __restrict__ partials, int nb) {
    __shared__ int tmp[256];
    int t = threadIdx.x;
    int v = (t < nb) ? partials[t] : 0;
    tmp[t] = v;
    __syncthreads();
    for (int off = 1; off < 256; off <<= 1) {
        int u = (t >= off) ? tmp[t - off] : 0;
        __syncthreads();
        tmp[t] += u;
        __syncthreads();
    }
    if (t < nb) partials[t] = tmp[t] - v;  // exclusive
}

__device__ __forceinline__ int sm_at(const int* __restrict__ scan_mat,
                                     const int* __restrict__ partials, int i) {
    return scan_mat[i] + partials[i >> 10];
}

// ---------------- phase 2: scatter edges into bucket-sorted streams ------
// dst stream: u32 (dst&255)<<17|src at [0,E). src stream: u8 (src&255) at [0,E).
__global__ __launch_bounds__(256) void bucket_scatter(const int* __restrict__ esrc,
                                                      const int* __restrict__ edst,
                                                      const int* __restrict__ scan_mat,
                                                      const int* __restrict__ partials,
                                                      unsigned int* __restrict__ tmp,
                                                      unsigned char* __restrict__ tmp2) {
    __shared__ int cd[NBUCK], cs[NBUCK];
    const int b = blockIdx.x, t = threadIdx.x;
    for (int i = t; i < NBUCK; i += 256) {
        cd[i] = sm_at(scan_mat, partials, i * NBLK + b);
        cs[i] = sm_at(scan_mat, partials, MATP + i * NBLK + b) - N_EDGES;
    }
    __syncthreads();
    const int e1 = (b + 1) * CHUNK;
    for (int e = b * CHUNK + t; e < e1; e += 256) {
        int s = esrc[e], d = edst[e];
        int pd = atomicAdd(&cd[d >> 8], 1);
        tmp[pd] = ((unsigned int)(d & 255) << 17) | (unsigned int)s;
        int ps = atomicAdd(&cs[s >> 8], 1);
        tmp2[ps] = (unsigned char)(s & 255);
    }
}

// ---------------- phase 3: fused per-bucket finalize (dst + src) ---------
__global__ __launch_bounds__(256) void finalize_fused(
    const unsigned int* __restrict__ tmp,
    const unsigned char* __restrict__ tmp2,
    const int* __restrict__ scan_mat,
    const int* __restrict__ partials,
    int* __restrict__ rowptr,
    int* __restrict__ csr_src,
    float* __restrict__ ndst,
    float* __restrict__ nsrc)
{
    __shared__ int hist[256];
    __shared__ int scn[256];
    __shared__ int cur[256];
    const int bb = blockIdx.x, t = threadIdx.x;
    if (bb < NBUCK) {
        const int b = bb;
        const int beg = sm_at(scan_mat, partials, b * 256);
        const int end = sm_at(scan_mat, partials, (b + 1) * 256);
        hist[t] = 0;
        __syncthreads();
        for (int j = beg + t; j < end; j += 256)
            atomicAdd(&hist[tmp[j] >> 17], 1);
        __syncthreads();
        int v = hist[t];
        scn[t] = v;
        __syncthreads();
        for (int off = 1; off < 256; off <<= 1) {
            int u = (t >= off) ? scn[t - off] : 0;
            __syncthreads();
            scn[t] += u;
            __syncthreads();
        }
        int excl = scn[t] - v;
        int node = b * 256 + t;
        if (node <= N_NODES) rowptr[node] = beg + excl;
        if (node < N_NODES) ndst[node] = rsqrtf(fmaxf((float)v, 1.0f));
        cur[t] = beg + excl;
        __syncthreads();
        for (int j = beg + t; j < end; j += 256) {
            unsigned int x = tmp[j];
            int pos = atomicAdd(&cur[x >> 17], 1);
            csr_src[pos] = (int)(x & 0x1FFFFu);
        }
    } else {
        const int b = bb - NBUCK;
        const int beg = sm_at(scan_mat, partials, MATP + b * 256) - N_EDGES;
        const int end = (b < NBUCK - 1)
                          ? sm_at(scan_mat, partials, MATP + (b + 1) * 256) - N_EDGES
                          : N_EDGES;
        hist[t] = 0;
        __syncthreads();
        for (int j = beg + t; j < end; j += 256)
            atomicAdd(&hist[tmp2[j]], 1);
        __syncthreads();
        int node = b * 256 + t;
        if (node < N_NODES) nsrc[node] = rsqrtf(fmaxf((float)hist[t], 1.0f));
    }
}

// ---------------- MFMA GEMM, f16 operands, f32 accumulate ----------------
// BM=64, BN=128, BK=64; 4 waves (2x2); 2 barriers per 64-K (halved vs BK=32).
// Layer 1 (AT=float, ATERMS=2): A = ah + al (two f16, exact to 2^-22); W = f16.
// Layer 2 (AT=f16, ATERMS=1): A exact f16, single term.
// LDS slot-major [slot][row/col][8]; slot strides 520/1032 f16 keep both the
// 16B writes and reads at exactly-minimal uniform banking (4*(slot+row) mod 32).
template<int K, int ATERMS, typename AT>
__global__ __launch_bounds__(256) void gemm_mfma(
    const AT* __restrict__ A,               // [M, K]
    const _Float16* __restrict__ WTf,       // [128][K] f16 (transposed W)
    const float* __restrict__ rowscale,     // [M]
    _Float16* __restrict__ C16,             // [M, 128] f16 out
    int M)
{
    constexpr int ASTR = 520;   // 64*8 + 8
    constexpr int BSTR = 1032;  // 128*8 + 8
    __shared__ _Float16 Ah[8 * ASTR];
    __shared__ _Float16 Al[ATERMS == 2 ? 8 * ASTR : 8];
    __shared__ _Float16 Bf[8 * BSTR];

    const int tid = threadIdx.x;
    const int bm = blockIdx.x * 64;
    const int lane = tid & 63;
    const int wid = tid >> 6;
    const int wm = wid >> 1;
    const int wn = wid & 1;
    const int lr = lane & 15;
    const int lg = lane >> 4;

    f32x4 acc[2][4];
    #pragma unroll
    for (int i = 0; i < 2; ++i)
        #pragma unroll
        for (int j = 0; j < 4; ++j)
            acc[i][j] = (f32x4){0.f, 0.f, 0.f, 0.f};

    // staging: A 2 chunks/thread (64 rows x 8 slots); B 4 chunks/thread (128 x 8)
    float avreg[2][8];
    f16x8 areg16[2];
    f16x8 bv[4];

    auto load_tile = [&](int k0) {
        #pragma unroll
        for (int i = 0; i < 2; ++i) {
            int lin = tid + i * 256;
            int row = lin >> 3;
            int s8  = lin & 7;
            int rg  = bm + row;
            if (rg < M) {
                const AT* ap = &A[(size_t)rg * K + k0 + s8 * 8];
                if constexpr (sizeof(AT) == 4) {
                    float4 v0 = *reinterpret_cast<const float4*>(ap);
                    float4 v1 = *reinterpret_cast<const float4*>(ap + 4);
                    avreg[i][0] = v0.x; avreg[i][1] = v0.y; avreg[i][2] = v0.z; avreg[i][3] = v0.w;
                    avreg[i][4] = v1.x; avreg[i][5] = v1.y; avreg[i][6] = v1.z; avreg[i][7] = v1.w;
                } else {
                    areg16[i] = *reinterpret_cast<const f16x8*>(ap);
                }
            } else {
                if constexpr (sizeof(AT) == 4) {
                    #pragma unroll
                    for (int j = 0; j < 8; ++j) avreg[i][j] = 0.f;
                } else {
                    #pragma unroll
                    for (int j = 0; j < 8; ++j) areg16[i][j] = (_Float16)0.f;
                }
            }
        }
        #pragma unroll
        for (int i = 0; i < 4; ++i) {
            int lin = tid + i * 256;
            int col = lin >> 3;
            int s8  = lin & 7;
            bv[i] = *reinterpret_cast<const f16x8*>(&WTf[(size_t)col * K + k0 + s8 * 8]);
        }
    };

    load_tile(0);

    for (int k0 = 0; k0 < K; k0 += 64) {
        // ---- write LDS from regs ----
        {
            #pragma unroll
            for (int i = 0; i < 2; ++i) {
                int lin = tid + i * 256;
                int row = lin >> 3;
                int s8  = lin & 7;
                int off = s8 * ASTR + row * 8;
                if constexpr (sizeof(AT) == 4) {
                    f16x8 vh, vl;
                    #pragma unroll
                    for (int j = 0; j < 8; ++j) {
                        _Float16 h = (_Float16)avreg[i][j];
                        vh[j] = h;
                        vl[j] = (_Float16)(avreg[i][j] - (float)h);
                    }
                    *reinterpret_cast<f16x8*>(&Ah[off]) = vh;
                    if constexpr (ATERMS == 2)
                        *reinterpret_cast<f16x8*>(&Al[off]) = vl;
                } else {
                    *reinterpret_cast<f16x8*>(&Ah[off]) = areg16[i];
                }
            }
            #pragma unroll
            for (int i = 0; i < 4; ++i) {
                int lin = tid + i * 256;
                int col = lin >> 3;
                int s8  = lin & 7;
                *reinterpret_cast<f16x8*>(&Bf[s8 * BSTR + col * 8]) = bv[i];
            }
        }
        __syncthreads();

        if (k0 + 64 < K) load_tile(k0 + 64);

        // ---- MFMA: two K=32 substeps ----
        #pragma unroll
        for (int ks = 0; ks < 2; ++ks) {
            const int slot = ks * 4 + lg;
            f16x8 afh[2], afl[2], bf[4];
            #pragma unroll
            for (int mt = 0; mt < 2; ++mt) {
                int row = wm * 32 + mt * 16 + lr;
                int off = slot * ASTR + row * 8;
                afh[mt] = *reinterpret_cast<const f16x8*>(&Ah[off]);
                if constexpr (ATERMS == 2)
                    afl[mt] = *reinterpret_cast<const f16x8*>(&Al[off]);
            }
            #pragma unroll
            for (int nt = 0; nt < 4; ++nt) {
                int col = wn * 64 + nt * 16 + lr;
                bf[nt] = *reinterpret_cast<const f16x8*>(&Bf[slot * BSTR + col * 8]);
            }
            #pragma unroll
            for (int mt = 0; mt < 2; ++mt) {
                #pragma unroll
                for (int nt = 0; nt < 4; ++nt) {
                    acc[mt][nt] = __builtin_amdgcn_mfma_f32_16x16x32_f16(
                        afh[mt], bf[nt], acc[mt][nt], 0, 0, 0);
                    if constexpr (ATERMS == 2)
                        acc[mt][nt] = __builtin_amdgcn_mfma_f32_16x16x32_f16(
                            afl[mt], bf[nt], acc[mt][nt], 0, 0, 0);
                }
            }
        }
        __syncthreads();
    }

    #pragma unroll
    for (int mt = 0; mt < 2; ++mt) {
        #pragma unroll
        for (int r = 0; r < 4; ++r) {
            int row = bm + wm * 32 + mt * 16 + lg * 4 + r;
            if (row < M) {
                float s = rowscale[row];
                #pragma unroll
                for (int nt = 0; nt < 4; ++nt) {
                    int col = wn * 64 + nt * 16 + lr;
                    C16[(size_t)row * 128 + col] = (_Float16)(acc[mt][nt][r] * s);
                }
            }
        }
    }
}

// ---------------- CSR aggregation, 16 lanes/node single pass -------------
template<typename OT>
__global__ __launch_bounds__(256) void aggregate16(
    const _Float16* __restrict__ h16,
    const int* __restrict__ rowptr,
    const int* __restrict__ csr_src,
    const float* __restrict__ ndst,
    const float* __restrict__ bias,
    OT* __restrict__ out, int N)
{
    int g = blockIdx.x * blockDim.x + threadIdx.x;
    int node = g >> 4;
    if (node >= N) return;
    int c8 = (g & 15) * 8;
    int beg = rowptr[node];
    int end = rowptr[node + 1];
    float acc[8] = {0.f, 0.f, 0.f, 0.f, 0.f, 0.f, 0.f, 0.f};
    int j = beg;
    for (; j + 3 < end; j += 4) {
        int s0 = csr_src[j];
        int s1 = csr_src[j + 1];
        int s2 = csr_src[j + 2];
        int s3 = csr_src[j + 3];
        f16x8 v0 = *reinterpret_cast<const f16x8*>(&h16[(size_t)s0 * 128 + c8]);
        f16x8 v1 = *reinterpret_cast<const f16x8*>(&h16[(size_t)s1 * 128 + c8]);
        f16x8 v2 = *reinterpret_cast<const f16x8*>(&h16[(size_t)s2 * 128 + c8]);
        f16x8 v3 = *reinterpret_cast<const f16x8*>(&h16[(size_t)s3 * 128 + c8]);
        #pragma unroll
        for (int k = 0; k < 8; ++k)
            acc[k] += ((float)v0[k] + (float)v1[k]) + ((float)v2[k] + (float)v3[k]);
    }
    for (; j < end; ++j) {
        int s0 = csr_src[j];
        f16x8 v0 = *reinterpret_cast<const f16x8*>(&h16[(size_t)s0 * 128 + c8]);
        #pragma unroll
        for (int k = 0; k < 8; ++k) acc[k] += (float)v0[k];
    }
    float sc = ndst[node];
    const float4 b0 = *reinterpret_cast<const float4*>(&bias[c8]);
    const float4 b1 = *reinterpret_cast<const float4*>(&bias[c8 + 4]);
    float r[8];
    r[0] = fmaxf(acc[0] * sc + b0.x, 0.f);
    r[1] = fmaxf(acc[1] * sc + b0.y, 0.f);
    r[2] = fmaxf(acc[2] * sc + b0.z, 0.f);
    r[3] = fmaxf(acc[3] * sc + b0.w, 0.f);
    r[4] = fmaxf(acc[4] * sc + b1.x, 0.f);
    r[5] = fmaxf(acc[5] * sc + b1.y, 0.f);
    r[6] = fmaxf(acc[6] * sc + b1.z, 0.f);
    r[7] = fmaxf(acc[7] * sc + b1.w, 0.f);
    OT* op = &out[(size_t)node * 128 + c8];
    if constexpr (sizeof(OT) == 4) {
        float4 r0 = {r[0], r[1], r[2], r[3]};
        float4 r1 = {r[4], r[5], r[6], r[7]};
        *reinterpret_cast<float4*>(op) = r0;
        *reinterpret_cast<float4*>(op + 4) = r1;
    } else {
        f16x8 rv;
        #pragma unroll
        for (int k = 0; k < 8; ++k) rv[k] = (_Float16)r[k];
        *reinterpret_cast<f16x8*>(op) = rv;
    }
}

extern "C" void kernel_launch(void* const* d_in, const int* in_sizes, int n_in,
                              void* d_out, int out_size, void* d_ws, size_t ws_size,
                              hipStream_t stream) {
    const float* feat = (const float*)d_in[0];   // [1, N, 256]
    const float* W1   = (const float*)d_in[1];   // [256, 128]
    const float* b1   = (const float*)d_in[2];   // [128]
    const float* W2   = (const float*)d_in[3];   // [128, 128]
    const float* b2   = (const float*)d_in[4];   // [128]
    const int* esrc   = (const int*)d_in[5];     // [E]
    const int* edst   = (const int*)d_in[6];     // [E]
    float* out = (float*)d_out;                  // [N, 128]

    const int Nn = N_NODES, E = N_EDGES;
    const int SCAN_N = 2 * MATP;                 // 200192
    const int SCAN_NB = (SCAN_N + 1023) / 1024;  // 196

    // workspace: h slot (N*128 f32-sized) holds h16 + h1out (both f16)
    float* hseg   = (float*)d_ws;
    _Float16* h16   = (_Float16*)hseg;
    _Float16* h1out = h16 + (size_t)Nn * 128;
    _Float16* WT1f = (_Float16*)(hseg + (size_t)Nn * 128);
    _Float16* WT2f = WT1f + 128 * 256;
    int* csr_src  = (int*)(WT2f + 128 * 128);
    int* rowptr   = csr_src + E;
    unsigned int* tmp = (unsigned int*)(rowptr + 100004);
    unsigned char* tmp2 = (unsigned char*)(tmp + (size_t)E);
    int* cnt_mat  = (int*)(tmp2 + (((size_t)E + 15) & ~15ull));
    int* scan_mat = cnt_mat + SCAN_N;
    int* partials = scan_mat + SCAN_N;
    float* nsrc   = (float*)(partials + ((SCAN_NB + 3) & ~3));
    float* ndst   = nsrc + Nn;

    // --- setup: bucket histograms + weight transpose (f16) fused ---
    fused_setup<<<NBLK + 192, 256, 0, stream>>>(esrc, edst, cnt_mat, W1, WT1f, W2, WT2f);

    // --- scan ---
    scan_blocks<<<SCAN_NB, 1024, 0, stream>>>(cnt_mat, scan_mat, partials, SCAN_N);
    scan_partials<<<1, 256, 0, stream>>>(partials, SCAN_NB);

    // --- scatter + fused finalize ---
    bucket_scatter<<<NBLK, 256, 0, stream>>>(esrc, edst, scan_mat, partials, tmp, tmp2);
    finalize_fused<<<2 * NBUCK, 256, 0, stream>>>(tmp, tmp2, scan_mat, partials,
                                                  rowptr, csr_src, ndst, nsrc);

    const int gemm_grid = (Nn + 63) / 64;         // 1563
    const int agg_grid  = (Nn * 16 + 255) / 256;  // 6250

    // --- layer 1: gemm (A f32, 2-term) -> h16; aggregate -> h1out (f16) ---
    gemm_mfma<256, 2, float><<<gemm_grid, 256, 0, stream>>>(feat, WT1f, nsrc, h16, Nn);
    aggregate16<_Float16><<<agg_grid, 256, 0, stream>>>(
        h16, rowptr, csr_src, ndst, b1, h1out, Nn);

    // --- layer 2: gemm (A f16, 1-term) -> h16; aggregate -> d_out (f32) ---
    gemm_mfma<128, 1, _Float16><<<gemm_grid, 256, 0, stream>>>(h1out, WT2f, nsrc, h16, Nn);
    aggregate16<float><<<agg_grid, 256, 0, stream>>>(
        h16, rowptr, csr_src, ndst, b2, out, Nn);
}

// Round 15
// 219.778 us; speedup vs baseline: 1.1108x; 1.0252x over previous
//
#include <hip/hip_runtime.h>
#include <hip/hip_bf16.h>

#define N_NODES 100000
#define N_EDGES 1600000
#define NBUCK 391          // ceil(N_NODES / 256)
#define NBLK 256           // bucket-phase blocks
#define CHUNK (N_EDGES / NBLK)   // 6250, exact
#define MATP (NBUCK * NBLK)      // 100096, per-part count-matrix size
#define GEMM_GRID 1563           // ceil(N_NODES/64)
#define GA 782                   // gemm1 part-A blocks (with scatter)
#define GB (GEMM_GRID - GA)      // 781, part-B (with finalize)

typedef float f32x4 __attribute__((ext_vector_type(4)));
typedef _Float16 f16x8 __attribute__((ext_vector_type(8)));

// ---------------- fused setup: bucket histograms + weight transpose (f16) --
__device__ __forceinline__ void wt_elem(const float* __restrict__ W,
                                        _Float16* __restrict__ WTf,
                                        int K, int i) {
    int col = i / K, k = i - col * K;
    WTf[i] = (_Float16)W[(size_t)k * 128 + col];
}

__global__ __launch_bounds__(256) void fused_setup(
    const int* __restrict__ esrc, const int* __restrict__ edst,
    int* __restrict__ cnt_mat,
    const float* __restrict__ W1, _Float16* __restrict__ WT1f,
    const float* __restrict__ W2, _Float16* __restrict__ WT2f)
{
    __shared__ int hd[NBUCK], hs[NBUCK];
    const int b = blockIdx.x, t = threadIdx.x;
    if (b < NBLK) {
        for (int i = t; i < NBUCK; i += 256) { hd[i] = 0; hs[i] = 0; }
        __syncthreads();
        const int e1 = (b + 1) * CHUNK;
        for (int e = b * CHUNK + t; e < e1; e += 256) {
            atomicAdd(&hd[edst[e] >> 8], 1);
            atomicAdd(&hs[esrc[e] >> 8], 1);
        }
        __syncthreads();
        for (int i = t; i < NBUCK; i += 256) {
            cnt_mat[i * NBLK + b] = hd[i];
            cnt_mat[MATP + i * NBLK + b] = hs[i];
        }
    } else {
        int i = (b - NBLK) * 256 + t;         // 0..49151
        if (i < 128 * 256) {
            wt_elem(W1, WT1f, 256, i);
        } else {
            int j = i - 128 * 256;            // < 16384
            wt_elem(W2, WT2f, 128, j);
        }
    }
}

// ---------------- flat exclusive scan (partials applied inline) ----------
__global__ __launch_bounds__(1024) void scan_blocks(const int* __restrict__ counts,
                                                    int* __restrict__ out,
                                                    int* __restrict__ partials, int n) {
    __shared__ int tmp[1024];
    int i = blockIdx.x * 1024 + threadIdx.x;
    int v = (i < n) ? counts[i] : 0;
    tmp[threadIdx.x] = v;
    __syncthreads();
    for (int off = 1; off < 1024; off <<= 1) {
        int t = (threadIdx.x >= (unsigned)off) ? tmp[threadIdx.x - off] : 0;
        __syncthreads();
        tmp[threadIdx.x] += t;
        __syncthreads();
    }
    if (i < n) out[i] = tmp[threadIdx.x] - v;
    if (threadIdx.x == 1023) partials[blockIdx.x] = tmp[1023];
}

__global__ __launch_bounds__(256) void scan_partials(int* __restrict__ partials, int nb) {
    __shared__ int tmp[256];
    int t = threadIdx.x;
    int v = (t < nb) ? partials[t] : 0;
    tmp[t] = v;
    __syncthreads();
    for (int off = 1; off < 256; off <<= 1) {
        int u = (t >= off) ? tmp[t - off] : 0;
        __syncthreads();
        tmp[t] += u;
        __syncthreads();
    }
    if (t < nb) partials[t] = tmp[t] - v;  // exclusive
}

__device__ __forceinline__ int sm_at(const int* __restrict__ scan_mat,
                                     const int* __restrict__ partials, int i) {
    return scan_mat[i] + partials[i >> 10];
}

// ---------------- GEMM body (device fn, shared-mem passed in) -------------
// BM=64, BN=128, BK=64; 4 waves. LDS slot-major, strides 520/1032 f16.
template<int K, int ATERMS, bool SCALE, typename AT>
__device__ __forceinline__ void gemm_body(
    char* __restrict__ smem_raw, int gblk,
    const AT* __restrict__ A, const _Float16* __restrict__ WTf,
    const float* __restrict__ rowscale, _Float16* __restrict__ C16, int M)
{
    constexpr int ASTR = 520;
    constexpr int BSTR = 1032;
    _Float16* Ah = (_Float16*)smem_raw;
    _Float16* Al = Ah + 8 * ASTR;                       // only used if ATERMS==2
    _Float16* Bf = (ATERMS == 2) ? (Al + 8 * ASTR) : Al;

    const int tid = threadIdx.x;
    const int bm = gblk * 64;
    const int lane = tid & 63;
    const int wid = tid >> 6;
    const int wm = wid >> 1;
    const int wn = wid & 1;
    const int lr = lane & 15;
    const int lg = lane >> 4;

    f32x4 acc[2][4];
    #pragma unroll
    for (int i = 0; i < 2; ++i)
        #pragma unroll
        for (int j = 0; j < 4; ++j)
            acc[i][j] = (f32x4){0.f, 0.f, 0.f, 0.f};

    float avreg[2][8];
    f16x8 areg16[2];
    f16x8 bv[4];

    auto load_tile = [&](int k0) {
        #pragma unroll
        for (int i = 0; i < 2; ++i) {
            int lin = tid + i * 256;
            int row = lin >> 3;
            int s8  = lin & 7;
            int rg  = bm + row;
            if (rg < M) {
                const AT* ap = &A[(size_t)rg * K + k0 + s8 * 8];
                if constexpr (sizeof(AT) == 4) {
                    float4 v0 = *reinterpret_cast<const float4*>(ap);
                    float4 v1 = *reinterpret_cast<const float4*>(ap + 4);
                    avreg[i][0] = v0.x; avreg[i][1] = v0.y; avreg[i][2] = v0.z; avreg[i][3] = v0.w;
                    avreg[i][4] = v1.x; avreg[i][5] = v1.y; avreg[i][6] = v1.z; avreg[i][7] = v1.w;
                } else {
                    areg16[i] = *reinterpret_cast<const f16x8*>(ap);
                }
            } else {
                if constexpr (sizeof(AT) == 4) {
                    #pragma unroll
                    for (int j = 0; j < 8; ++j) avreg[i][j] = 0.f;
                } else {
                    #pragma unroll
                    for (int j = 0; j < 8; ++j) areg16[i][j] = (_Float16)0.f;
                }
            }
        }
        #pragma unroll
        for (int i = 0; i < 4; ++i) {
            int lin = tid + i * 256;
            int col = lin >> 3;
            int s8  = lin & 7;
            bv[i] = *reinterpret_cast<const f16x8*>(&WTf[(size_t)col * K + k0 + s8 * 8]);
        }
    };

    load_tile(0);

    for (int k0 = 0; k0 < K; k0 += 64) {
        {
            #pragma unroll
            for (int i = 0; i < 2; ++i) {
                int lin = tid + i * 256;
                int row = lin >> 3;
                int s8  = lin & 7;
                int off = s8 * ASTR + row * 8;
                if constexpr (sizeof(AT) == 4) {
                    f16x8 vh, vl;
                    #pragma unroll
                    for (int j = 0; j < 8; ++j) {
                        _Float16 h = (_Float16)avreg[i][j];
                        vh[j] = h;
                        vl[j] = (_Float16)(avreg[i][j] - (float)h);
                    }
                    *reinterpret_cast<f16x8*>(&Ah[off]) = vh;
                    if constexpr (ATERMS == 2)
                        *reinterpret_cast<f16x8*>(&Al[off]) = vl;
                } else {
                    *reinterpret_cast<f16x8*>(&Ah[off]) = areg16[i];
                }
            }
            #pragma unroll
            for (int i = 0; i < 4; ++i) {
                int lin = tid + i * 256;
                int col = lin >> 3;
                int s8  = lin & 7;
                *reinterpret_cast<f16x8*>(&Bf[s8 * BSTR + col * 8]) = bv[i];
            }
        }
        __syncthreads();

        if (k0 + 64 < K) load_tile(k0 + 64);

        #pragma unroll
        for (int ks = 0; ks < 2; ++ks) {
            const int slot = ks * 4 + lg;
            f16x8 afh[2], afl[2], bf[4];
            #pragma unroll
            for (int mt = 0; mt < 2; ++mt) {
                int row = wm * 32 + mt * 16 + lr;
                int off = slot * ASTR + row * 8;
                afh[mt] = *reinterpret_cast<const f16x8*>(&Ah[off]);
                if constexpr (ATERMS == 2)
                    afl[mt] = *reinterpret_cast<const f16x8*>(&Al[off]);
            }
            #pragma unroll
            for (int nt = 0; nt < 4; ++nt) {
                int col = wn * 64 + nt * 16 + lr;
                bf[nt] = *reinterpret_cast<const f16x8*>(&Bf[slot * BSTR + col * 8]);
            }
            #pragma unroll
            for (int mt = 0; mt < 2; ++mt) {
                #pragma unroll
                for (int nt = 0; nt < 4; ++nt) {
                    acc[mt][nt] = __builtin_amdgcn_mfma_f32_16x16x32_f16(
                        afh[mt], bf[nt], acc[mt][nt], 0, 0, 0);
                    if constexpr (ATERMS == 2)
                        acc[mt][nt] = __builtin_amdgcn_mfma_f32_16x16x32_f16(
                            afl[mt], bf[nt], acc[mt][nt], 0, 0, 0);
                }
            }
        }
        __syncthreads();
    }

    #pragma unroll
    for (int mt = 0; mt < 2; ++mt) {
        #pragma unroll
        for (int r = 0; r < 4; ++r) {
            int row = bm + wm * 32 + mt * 16 + lg * 4 + r;
            if (row < M) {
                float s = SCALE ? rowscale[row] : 1.0f;
                #pragma unroll
                for (int nt = 0; nt < 4; ++nt) {
                    int col = wn * 64 + nt * 16 + lr;
                    C16[(size_t)row * 128 + col] = (_Float16)(acc[mt][nt][r] * s);
                }
            }
        }
    }
}

// ---------------- scatter body ----------------
__device__ __forceinline__ void scatter_body(
    char* __restrict__ smem_raw, int b,
    const int* __restrict__ esrc, const int* __restrict__ edst,
    const int* __restrict__ scan_mat, const int* __restrict__ partials,
    unsigned int* __restrict__ tmp, unsigned char* __restrict__ tmp2)
{
    int* cd = (int*)smem_raw;
    int* cs = cd + NBUCK;
    const int t = threadIdx.x;
    for (int i = t; i < NBUCK; i += 256) {
        cd[i] = sm_at(scan_mat, partials, i * NBLK + b);
        cs[i] = sm_at(scan_mat, partials, MATP + i * NBLK + b) - N_EDGES;
    }
    __syncthreads();
    const int e1 = (b + 1) * CHUNK;
    for (int e = b * CHUNK + t; e < e1; e += 256) {
        int s = esrc[e], d = edst[e];
        int pd = atomicAdd(&cd[d >> 8], 1);
        tmp[pd] = ((unsigned int)(d & 255) << 17) | (unsigned int)s;
        int ps = atomicAdd(&cs[s >> 8], 1);
        tmp2[ps] = (unsigned char)(s & 255);
    }
}

// ---------------- finalize body (dst or src role) ----------------
__device__ __forceinline__ void finalize_body(
    char* __restrict__ smem_raw, int bb,
    const unsigned int* __restrict__ tmp, const unsigned char* __restrict__ tmp2,
    const int* __restrict__ scan_mat, const int* __restrict__ partials,
    int* __restrict__ rowptr, int* __restrict__ csr_src,
    float* __restrict__ ndst, float* __restrict__ nsrc)
{
    int* hist = (int*)smem_raw;
    int* scn  = hist + 256;
    int* cur  = scn + 256;
    const int t = threadIdx.x;
    if (bb < NBUCK) {
        const int b = bb;
        const int beg = sm_at(scan_mat, partials, b * 256);
        const int end = sm_at(scan_mat, partials, (b + 1) * 256);
        hist[t] = 0;
        __syncthreads();
        for (int j = beg + t; j < end; j += 256)
            atomicAdd(&hist[tmp[j] >> 17], 1);
        __syncthreads();
        int v = hist[t];
        scn[t] = v;
        __syncthreads();
        for (int off = 1; off < 256; off <<= 1) {
            int u = (t >= off) ? scn[t - off] : 0;
            __syncthreads();
            scn[t] += u;
            __syncthreads();
        }
        int excl = scn[t] - v;
        int node = b * 256 + t;
        if (node <= N_NODES) rowptr[node] = beg + excl;
        if (node < N_NODES) ndst[node] = rsqrtf(fmaxf((float)v, 1.0f));
        cur[t] = beg + excl;
        __syncthreads();
        for (int j = beg + t; j < end; j += 256) {
            unsigned int x = tmp[j];
            int pos = atomicAdd(&cur[x >> 17], 1);
            csr_src[pos] = (int)(x & 0x1FFFFu);
        }
    } else {
        const int b = bb - NBUCK;
        const int beg = sm_at(scan_mat, partials, MATP + b * 256) - N_EDGES;
        const int end = (b < NBUCK - 1)
                          ? sm_at(scan_mat, partials, MATP + (b + 1) * 256) - N_EDGES
                          : N_EDGES;
        hist[t] = 0;
        __syncthreads();
        for (int j = beg + t; j < end; j += 256)
            atomicAdd(&hist[tmp2[j]], 1);
        __syncthreads();
        int node = b * 256 + t;
        if (node < N_NODES) nsrc[node] = rsqrtf(fmaxf((float)hist[t], 1.0f));
    }
}

// ---------------- combined dispatch 1: scatter || gemm1 part A ------------
__global__ __launch_bounds__(256) void scatter_gemmA(
    const int* __restrict__ esrc, const int* __restrict__ edst,
    const int* __restrict__ scan_mat, const int* __restrict__ partials,
    unsigned int* __restrict__ tmp, unsigned char* __restrict__ tmp2,
    const float* __restrict__ feat, const _Float16* __restrict__ WT1f,
    _Float16* __restrict__ h16, int N)
{
    __shared__ __align__(16) char smem[33152];
    if (blockIdx.x < NBLK)
        scatter_body(smem, blockIdx.x, esrc, edst, scan_mat, partials, tmp, tmp2);
    else
        gemm_body<256, 2, false, float>(smem, blockIdx.x - NBLK, feat, WT1f,
                                        nullptr, h16, N);
}

// ---------------- combined dispatch 2: finalize || gemm1 part B -----------
__global__ __launch_bounds__(256) void finalize_gemmB(
    const unsigned int* __restrict__ tmp, const unsigned char* __restrict__ tmp2,
    const int* __restrict__ scan_mat, const int* __restrict__ partials,
    int* __restrict__ rowptr, int* __restrict__ csr_src,
    float* __restrict__ ndst, float* __restrict__ nsrc,
    const float* __restrict__ feat, const _Float16* __restrict__ WT1f,
    _Float16* __restrict__ h16, int N)
{
    __shared__ __align__(16) char smem[33152];
    if (blockIdx.x < 2 * NBUCK)
        finalize_body(smem, blockIdx.x, tmp, tmp2, scan_mat, partials,
                      rowptr, csr_src, ndst, nsrc);
    else
        gemm_body<256, 2, false, float>(smem, GA + (blockIdx.x - 2 * NBUCK),
                                        feat, WT1f, nullptr, h16, N);
}

// ---------------- layer-2 gemm (standalone) ----------------
__global__ __launch_bounds__(256) void gemm2_kernel(
    const _Float16* __restrict__ A, const _Float16* __restrict__ WTf,
    const float* __restrict__ rowscale, _Float16* __restrict__ C16, int M)
{
    __shared__ __align__(16) char smem[24832];
    gemm_body<128, 1, true, _Float16>(smem, blockIdx.x, A, WTf, rowscale, C16, M);
}

// ---------------- CSR aggregation, 16 lanes/node ----------------
// SRCSCALE: multiply each gathered row by nsrc[src] (deferred gemm1 row-scale).
template<typename OT, bool SRCSCALE>
__global__ __launch_bounds__(256) void aggregate16(
    const _Float16* __restrict__ h16,
    const int* __restrict__ rowptr,
    const int* __restrict__ csr_src,
    const float* __restrict__ nsrc,
    const float* __restrict__ ndst,
    const float* __restrict__ bias,
    OT* __restrict__ out, int N)
{
    int g = blockIdx.x * blockDim.x + threadIdx.x;
    int node = g >> 4;
    if (node >= N) return;
    int c8 = (g & 15) * 8;
    int beg = rowptr[node];
    int end = rowptr[node + 1];
    float acc[8] = {0.f, 0.f, 0.f, 0.f, 0.f, 0.f, 0.f, 0.f};
    int j = beg;
    for (; j + 3 < end; j += 4) {
        int s0 = csr_src[j];
        int s1 = csr_src[j + 1];
        int s2 = csr_src[j + 2];
        int s3 = csr_src[j + 3];
        f16x8 v0 = *reinterpret_cast<const f16x8*>(&h16[(size_t)s0 * 128 + c8]);
        f16x8 v1 = *reinterpret_cast<const f16x8*>(&h16[(size_t)s1 * 128 + c8]);
        f16x8 v2 = *reinterpret_cast<const f16x8*>(&h16[(size_t)s2 * 128 + c8]);
        f16x8 v3 = *reinterpret_cast<const f16x8*>(&h16[(size_t)s3 * 128 + c8]);
        if constexpr (SRCSCALE) {
            float n0 = nsrc[s0], n1 = nsrc[s1], n2 = nsrc[s2], n3 = nsrc[s3];
            #pragma unroll
            for (int k = 0; k < 8; ++k)
                acc[k] += ((float)v0[k] * n0 + (float)v1[k] * n1)
                        + ((float)v2[k] * n2 + (float)v3[k] * n3);
        } else {
            #pragma unroll
            for (int k = 0; k < 8; ++k)
                acc[k] += ((float)v0[k] + (float)v1[k]) + ((float)v2[k] + (float)v3[k]);
        }
    }
    for (; j < end; ++j) {
        int s0 = csr_src[j];
        f16x8 v0 = *reinterpret_cast<const f16x8*>(&h16[(size_t)s0 * 128 + c8]);
        if constexpr (SRCSCALE) {
            float n0 = nsrc[s0];
            #pragma unroll
            for (int k = 0; k < 8; ++k) acc[k] += (float)v0[k] * n0;
        } else {
            #pragma unroll
            for (int k = 0; k < 8; ++k) acc[k] += (float)v0[k];
        }
    }
    float sc = ndst[node];
    const float4 b0 = *reinterpret_cast<const float4*>(&bias[c8]);
    const float4 b1 = *reinterpret_cast<const float4*>(&bias[c8 + 4]);
    float r[8];
    r[0] = fmaxf(acc[0] * sc + b0.x, 0.f);
    r[1] = fmaxf(acc[1] * sc + b0.y, 0.f);
    r[2] = fmaxf(acc[2] * sc + b0.z, 0.f);
    r[3] = fmaxf(acc[3] * sc + b0.w, 0.f);
    r[4] = fmaxf(acc[4] * sc + b1.x, 0.f);
    r[5] = fmaxf(acc[5] * sc + b1.y, 0.f);
    r[6] = fmaxf(acc[6] * sc + b1.z, 0.f);
    r[7] = fmaxf(acc[7] * sc + b1.w, 0.f);
    OT* op = &out[(size_t)node * 128 + c8];
    if constexpr (sizeof(OT) == 4) {
        float4 r0 = {r[0], r[1], r[2], r[3]};
        float4 r1 = {r[4], r[5], r[6], r[7]};
        *reinterpret_cast<float4*>(op) = r0;
        *reinterpret_cast<float4*>(op + 4) = r1;
    } else {
        f16x8 rv;
        #pragma unroll
        for (int k = 0; k < 8; ++k) rv[k] = (_Float16)r[k];
        *reinterpret_cast<f16x8*>(op) = rv;
    }
}

extern "C" void kernel_launch(void* const* d_in, const int* in_sizes, int n_in,
                              void* d_out, int out_size, void* d_ws, size_t ws_size,
                              hipStream_t stream) {
    const float* feat = (const float*)d_in[0];   // [1, N, 256]
    const float* W1   = (const float*)d_in[1];   // [256, 128]
    const float* b1   = (const float*)d_in[2];   // [128]
    const float* W2   = (const float*)d_in[3];   // [128, 128]
    const float* b2   = (const float*)d_in[4];   // [128]
    const int* esrc   = (const int*)d_in[5];     // [E]
    const int* edst   = (const int*)d_in[6];     // [E]
    float* out = (float*)d_out;                  // [N, 128]

    const int Nn = N_NODES, E = N_EDGES;
    const int SCAN_N = 2 * MATP;                 // 200192
    const int SCAN_NB = (SCAN_N + 1023) / 1024;  // 196

    // workspace: h slot (N*128 f32-sized) holds h16 + h1out (both f16)
    float* hseg   = (float*)d_ws;
    _Float16* h16   = (_Float16*)hseg;
    _Float16* h1out = h16 + (size_t)Nn * 128;
    _Float16* WT1f = (_Float16*)(hseg + (size_t)Nn * 128);
    _Float16* WT2f = WT1f + 128 * 256;
    int* csr_src  = (int*)(WT2f + 128 * 128);
    int* rowptr   = csr_src + E;
    unsigned int* tmp = (unsigned int*)(rowptr + 100004);
    unsigned char* tmp2 = (unsigned char*)(tmp + (size_t)E);
    int* cnt_mat  = (int*)(tmp2 + (((size_t)E + 15) & ~15ull));
    int* scan_mat = cnt_mat + SCAN_N;
    int* partials = scan_mat + SCAN_N;
    float* nsrc   = (float*)(partials + ((SCAN_NB + 3) & ~3));
    float* ndst   = nsrc + Nn;

    // --- setup: bucket histograms + weight transpose (f16) fused ---
    fused_setup<<<NBLK + 192, 256, 0, stream>>>(esrc, edst, cnt_mat, W1, WT1f, W2, WT2f);

    // --- scan ---
    scan_blocks<<<SCAN_NB, 1024, 0, stream>>>(cnt_mat, scan_mat, partials, SCAN_N);
    scan_partials<<<1, 256, 0, stream>>>(partials, SCAN_NB);

    // --- [scatter || gemm1-A] then [finalize || gemm1-B] ---
    scatter_gemmA<<<NBLK + GA, 256, 0, stream>>>(esrc, edst, scan_mat, partials,
                                                 tmp, tmp2, feat, WT1f, h16, Nn);
    finalize_gemmB<<<2 * NBUCK + GB, 256, 0, stream>>>(tmp, tmp2, scan_mat, partials,
                                                       rowptr, csr_src, ndst, nsrc,
                                                       feat, WT1f, h16, Nn);

    const int agg_grid = (Nn * 16 + 255) / 256;  // 6250

    // --- aggregate1 (applies deferred nsrc[src]) -> h1out (f16) ---
    aggregate16<_Float16, true><<<agg_grid, 256, 0, stream>>>(
        h16, rowptr, csr_src, nsrc, ndst, b1, h1out, Nn);

    // --- layer 2: gemm (A f16, 1-term, nsrc in epilogue) -> h16 ---
    gemm2_kernel<<<GEMM_GRID, 256, 0, stream>>>(h1out, WT2f, nsrc, h16, Nn);

    // --- aggregate2 -> d_out (f32) ---
    aggregate16<float, false><<<agg_grid, 256, 0, stream>>>(
        h16, rowptr, csr_src, nsrc, ndst, b2, out, Nn);
}